// Round 1
// baseline (194.800 us; speedup 1.0000x reference)
//
#include <hip/hip_runtime.h>

// K-manifold AE cluster objective, fused.
// out = mean_b min_k [ ||x_b||^2 - 2 w.z + z^T G z + lamb*reg_k ]
//   z = Vs[k] @ x_b (10), w = Us[k]^T @ x_b (10), G = Us^T Us (10x10)

#define KCLUST   16
#define DAMB     512
#define DLAT     10
#define BATCH    16384
#define NC       320          // KCLUST * 2 * DLAT
#define LAMBDA   0.01f

#define ROWS     32           // batch rows per block
#define KCH      32           // K-chunk staged in LDS
#define NTHREADS 256

// ---------------- pack W[D][320]: col = 20k+c ; c<10 -> Vs[k][c][D], else Us[k][D][c-10]
__global__ __launch_bounds__(256) void pack_w(const float* __restrict__ Us,
                                              const float* __restrict__ Vs,
                                              float* __restrict__ wp) {
    int idx = blockIdx.x * 256 + threadIdx.x;
    if (idx >= DAMB * NC) return;
    int Dv  = idx / NC;
    int col = idx % NC;
    int k = col / 20;
    int c = col % 20;
    float v;
    if (c < DLAT) v = Vs[(size_t)k * DLAT * DAMB + c * DAMB + Dv];
    else          v = Us[(size_t)k * DAMB * DLAT + Dv * DLAT + (c - DLAT)];
    wp[idx] = v;
}

// ---------------- G[k] = Us[k]^T Us[k] (10x10) and lamb*0.5*(|U|^2+|V|^2)
__global__ __launch_bounds__(128) void prep_g(const float* __restrict__ Us,
                                              const float* __restrict__ Vs,
                                              float* __restrict__ G,
                                              float* __restrict__ lreg) {
    __shared__ float red[128];
    int k = blockIdx.x;
    int tid = threadIdx.x;
    const float* Uk = Us + (size_t)k * DAMB * DLAT;
    const float* Vk = Vs + (size_t)k * DLAT * DAMB;
    float s = 0.f;
    for (int i = tid; i < DAMB * DLAT; i += 128) {
        float a = Uk[i], b = Vk[i];
        s += a * a + b * b;
    }
    red[tid] = s;
    __syncthreads();
    for (int st = 64; st > 0; st >>= 1) {
        if (tid < st) red[tid] += red[tid + st];
        __syncthreads();
    }
    if (tid == 0) lreg[k] = LAMBDA * 0.5f * red[0];
    if (tid < DLAT * DLAT) {
        int i = tid / DLAT, j = tid % DLAT;
        float g = 0.f;
        for (int Dv = 0; Dv < DAMB; ++Dv)
            g += Uk[Dv * DLAT + i] * Uk[Dv * DLAT + j];
        G[k * 100 + tid] = g;
    }
}

// ---------------- fused GEMM (Y = X W) + per-row objective + block reduce
__global__ __launch_bounds__(NTHREADS) void main_k(const float* __restrict__ x,
                                                   const float* __restrict__ wp,
                                                   const float* __restrict__ G,
                                                   const float* __restrict__ lreg,
                                                   float* __restrict__ parts) {
    __shared__ float xs[KCH][ROWS];      // 4 KB, x chunk transposed
    __shared__ float wl[KCH * NC];       // 40 KB W chunk; reused as Y[ROWS][NC]
    __shared__ float rowsq[ROWS];
    __shared__ float objl[ROWS][KCLUST];
    __shared__ float red[NTHREADS];

    const int tid = threadIdx.x;
    const int row0 = blockIdx.x * ROWS;
    const int rg = tid >> 6;             // 0..3  -> rows rg*8..+7
    const int cg = tid & 63;             // 0..63 -> cols cg+64j, j=0..4
    const int rs = tid >> 3;             // staging row 0..31
    const int c4 = tid & 7;              // staging float4 col

    float acc[8][5];
#pragma unroll
    for (int i = 0; i < 8; ++i)
#pragma unroll
        for (int j = 0; j < 5; ++j) acc[i][j] = 0.f;
    float rsq[8];
#pragma unroll
    for (int i = 0; i < 8; ++i) rsq[i] = 0.f;

    for (int kc = 0; kc < DAMB; kc += KCH) {
        // issue global loads for this chunk (before barrier so they overlap)
        float4 xv4 = *(const float4*)(x + (size_t)(row0 + rs) * DAMB + kc + 4 * c4);
        float4 wv4[10];
#pragma unroll
        for (int it = 0; it < 10; ++it) {
            int idx = it * NTHREADS + tid;                  // [0,2560)
            wv4[it] = *(const float4*)(wp + (size_t)(kc + idx / 80) * NC + (idx % 80) * 4);
        }
        __syncthreads();                 // previous chunk's reads complete
        xs[4 * c4 + 0][rs] = xv4.x;
        xs[4 * c4 + 1][rs] = xv4.y;
        xs[4 * c4 + 2][rs] = xv4.z;
        xs[4 * c4 + 3][rs] = xv4.w;
#pragma unroll
        for (int it = 0; it < 10; ++it) {
            int idx = it * NTHREADS + tid;
            *(float4*)(wl + (idx / 80) * NC + (idx % 80) * 4) = wv4[it];
        }
        __syncthreads();

        for (int c = 0; c < KCH; ++c) {
            float xv[8];
            *(float4*)&xv[0] = *(const float4*)&xs[c][rg * 8];
            *(float4*)&xv[4] = *(const float4*)&xs[c][rg * 8 + 4];
            float wv[5];
#pragma unroll
            for (int j = 0; j < 5; ++j) wv[j] = wl[c * NC + cg + 64 * j];
#pragma unroll
            for (int i = 0; i < 8; ++i)
#pragma unroll
                for (int j = 0; j < 5; ++j)
                    acc[i][j] = fmaf(xv[i], wv[j], acc[i][j]);
            if (cg == 0) {
#pragma unroll
                for (int i = 0; i < 8; ++i) rsq[i] = fmaf(xv[i], xv[i], rsq[i]);
            }
        }
    }
    __syncthreads();                     // all compute done before wl -> Y reuse

    // write Y tile (strided cols cg+64j)
#pragma unroll
    for (int i = 0; i < 8; ++i)
#pragma unroll
        for (int j = 0; j < 5; ++j)
            wl[(rg * 8 + i) * NC + cg + 64 * j] = acc[i][j];
    if (cg == 0) {
#pragma unroll
        for (int i = 0; i < 8; ++i) rowsq[rg * 8 + i] = rsq[i];
    }
    __syncthreads();

    // per-(row,k) objective: z^T G z - 2 w.z + lamb*reg
#pragma unroll
    for (int it = 0; it < 2; ++it) {
        int item = tid + it * NTHREADS;  // [0,512)
        int kk  = item & (KCLUST - 1);
        int row = item >> 4;
        const float* y = wl + row * NC + kk * 20;
        float z[DLAT], w[DLAT];
#pragma unroll
        for (int i = 0; i < DLAT; ++i) { z[i] = y[i]; w[i] = y[DLAT + i]; }
        const float* Gk = G + kk * 100;
        float s = 0.f, wz = 0.f;
#pragma unroll
        for (int i = 0; i < DLAT; ++i) {
            float gz = 0.f;
#pragma unroll
            for (int j = 0; j < DLAT; ++j) gz = fmaf(Gk[i * DLAT + j], z[j], gz);
            s  = fmaf(z[i], gz, s);
            wz = fmaf(w[i], z[i], wz);
        }
        objl[row][kk] = s - 2.f * wz + lreg[kk];
    }
    __syncthreads();

    float v = 0.f;
    if (tid < ROWS) {
        float m = objl[tid][0];
#pragma unroll
        for (int k = 1; k < KCLUST; ++k) m = fminf(m, objl[tid][k]);
        v = m + rowsq[tid];
    }
    red[tid] = v;
    __syncthreads();
    for (int st = NTHREADS / 2; st > 0; st >>= 1) {
        if (tid < st) red[tid] += red[tid + st];
        __syncthreads();
    }
    if (tid == 0) parts[blockIdx.x] = red[0];
}

// ---------------- final deterministic reduction over 512 block partials
__global__ __launch_bounds__(256) void finalize(const float* __restrict__ parts,
                                                float* __restrict__ out) {
    __shared__ float red[256];
    int tid = threadIdx.x;
    red[tid] = parts[tid] + parts[tid + 256];
    __syncthreads();
    for (int st = 128; st > 0; st >>= 1) {
        if (tid < st) red[tid] += red[tid + st];
        __syncthreads();
    }
    if (tid == 0) out[0] = red[0] * (1.0f / BATCH);
}

extern "C" void kernel_launch(void* const* d_in, const int* in_sizes, int n_in,
                              void* d_out, int out_size, void* d_ws, size_t ws_size,
                              hipStream_t stream) {
    const float* x  = (const float*)d_in[0];   // 16384 x 512
    const float* Us = (const float*)d_in[1];   // 16 x 512 x 10
    const float* Vs = (const float*)d_in[2];   // 16 x 10 x 512
    float* out = (float*)d_out;

    // workspace layout (floats): W[512*320] | G[16*100] | lreg[16] | parts[512]
    float* wp    = (float*)d_ws;
    float* G     = wp + DAMB * NC;
    float* lreg  = G + KCLUST * 100;
    float* parts = lreg + KCLUST;
    // requires 663,872 bytes of d_ws

    pack_w<<<(DAMB * NC + 255) / 256, 256, 0, stream>>>(Us, Vs, wp);
    prep_g<<<KCLUST, 128, 0, stream>>>(Us, Vs, G, lreg);
    main_k<<<BATCH / ROWS, NTHREADS, 0, stream>>>(x, wp, G, lreg, parts);
    finalize<<<1, 256, 0, stream>>>(parts, out);
}

// Round 2
// 68.717 us; speedup vs baseline: 2.8348x; 2.8348x over previous
//
#include <hip/hip_runtime.h>

// K-manifold AE cluster objective, fused, bf16-MFMA GEMM.
// out = mean_b min_k [ ||x_b||^2 - 2 w.z + z^T G z + lamb*reg_k ]
//   z = Vs[k] @ x_b (10), w = Us[k]^T @ x_b (10), G = Us^T Us (10x10)
// GEMM: Y[16384][320] = X[16384][512] @ W[512][320], W col 20k+c = Vs/Us concat.

#define KCLUST   16
#define DAMB     512
#define DLAT     10
#define BATCH    16384
#define NC       320
#define LAMBDA   0.01f

#define BM       32            // batch rows per block
#define NTHREADS 256
#define NKS      16            // 512 / 32 k-steps
#define NNT      20            // 320 / 16 n-tiles

typedef __attribute__((ext_vector_type(8))) short short8;
typedef __attribute__((ext_vector_type(4))) float f32x4;

__device__ inline short f2bf(float f) {
    unsigned u = __builtin_bit_cast(unsigned, f);
    unsigned r = (u + 0x7FFFu + ((u >> 16) & 1u)) >> 16;
    return (short)r;
}

// ---------------- pack W into bf16 MFMA B-fragment order: wpack[ks][nt][lane][8]
// B frag (16x16x32): lane l holds B[k = ks*32 + (l>>4)*8 + j][col = nt*16 + (l&15)]
__global__ __launch_bounds__(256) void pack_w(const float* __restrict__ Us,
                                              const float* __restrict__ Vs,
                                              short* __restrict__ wpack) {
    int idx = blockIdx.x * 256 + threadIdx.x;          // [0, 16*20*64)
    if (idx >= NKS * NNT * 64) return;
    int ks   = idx / (NNT * 64);
    int rem  = idx % (NNT * 64);
    int nt   = rem / 64;
    int lane = rem % 64;
    int col  = nt * 16 + (lane & 15);
    int cl   = col / 20;
    int c    = col % 20;
    short8 sv;
#pragma unroll
    for (int j = 0; j < 8; ++j) {
        int k = ks * 32 + (lane >> 4) * 8 + j;
        float v;
        if (c < DLAT) v = Vs[(size_t)cl * DLAT * DAMB + c * DAMB + k];
        else          v = Us[(size_t)cl * DAMB * DLAT + k * DLAT + (c - DLAT)];
        sv[j] = f2bf(v);
    }
    *(short8*)&wpack[(size_t)idx * 8] = sv;
}

// ---------------- G[k] = Us[k]^T Us[k] (10x10, fp32 exact) and lamb*0.5*(|U|^2+|V|^2)
__global__ __launch_bounds__(128) void prep_g(const float* __restrict__ Us,
                                              const float* __restrict__ Vs,
                                              float* __restrict__ G,
                                              float* __restrict__ lreg) {
    __shared__ float red[128];
    int k = blockIdx.x;
    int tid = threadIdx.x;
    const float* Uk = Us + (size_t)k * DAMB * DLAT;
    const float* Vk = Vs + (size_t)k * DLAT * DAMB;
    float s = 0.f;
    for (int i = tid; i < DAMB * DLAT; i += 128) {
        float a = Uk[i], b = Vk[i];
        s += a * a + b * b;
    }
    red[tid] = s;
    __syncthreads();
    for (int st = 64; st > 0; st >>= 1) {
        if (tid < st) red[tid] += red[tid + st];
        __syncthreads();
    }
    if (tid == 0) lreg[k] = LAMBDA * 0.5f * red[0];
    if (tid < DLAT * DLAT) {
        int i = tid / DLAT, j = tid % DLAT;
        float g = 0.f;
        for (int Dv = 0; Dv < DAMB; ++Dv)
            g += Uk[Dv * DLAT + i] * Uk[Dv * DLAT + j];
        G[k * 100 + tid] = g;
    }
}

// ---------------- main: bf16 MFMA GEMM + objective + min + block reduce
__global__ __launch_bounds__(NTHREADS) void main_k(const float* __restrict__ x,
                                                   const short* __restrict__ wpack,
                                                   const float* __restrict__ G,
                                                   const float* __restrict__ lreg,
                                                   float* __restrict__ parts) {
    __shared__ short a_lds[2 * NKS * 64 * 8];   // 32 KB, A frags [mt][ks][lane][8]
    __shared__ char  bY[40960];                 // 40 KB: B chunk (bf16) / Y[32][320] f32
    __shared__ float rsqp[32][8];
    __shared__ float rowsq_s[32];
    __shared__ float objl[32][KCLUST];
    __shared__ float red[NTHREADS];

    const int tid  = threadIdx.x;
    const int lane = tid & 63;
    const int wv   = tid >> 6;                  // wave 0..3, owns n-tiles wv*5..wv*5+4
    const int row0 = blockIdx.x * BM;

    // ---- stage A (fp32 -> bf16, fragment order) + exact fp32 rowsq
    {
        const int srow = tid >> 3;              // 0..31
        const int sc   = tid & 7;               // 0..7
        const int mt   = srow >> 4;
        const int rlo  = srow & 15;
        const float* xr = x + (size_t)(row0 + srow) * DAMB;
        float rs = 0.f;
#pragma unroll
        for (int i = 0; i < 8; ++i) {
            int k8 = sc + 8 * i;                // 8-elem group, 0..63
            float4 v0 = *(const float4*)(xr + k8 * 8);
            float4 v1 = *(const float4*)(xr + k8 * 8 + 4);
            rs += v0.x * v0.x + v0.y * v0.y + v0.z * v0.z + v0.w * v0.w
                + v1.x * v1.x + v1.y * v1.y + v1.z * v1.z + v1.w * v1.w;
            short8 sv;
            sv[0] = f2bf(v0.x); sv[1] = f2bf(v0.y); sv[2] = f2bf(v0.z); sv[3] = f2bf(v0.w);
            sv[4] = f2bf(v1.x); sv[5] = f2bf(v1.y); sv[6] = f2bf(v1.z); sv[7] = f2bf(v1.w);
            int ks = k8 >> 2, lh = k8 & 3;
            int ln = (lh << 4) | rlo;
            *(short8*)&a_lds[((mt * NKS + ks) * 64 + ln) * 8] = sv;
        }
        rsqp[srow][sc] = rs;
    }
    __syncthreads();
    if (tid < 32) {
        float s = 0.f;
#pragma unroll
        for (int j = 0; j < 8; ++j) s += rsqp[tid][j];
        rowsq_s[tid] = s;
    }

    // ---- K loop: 8 chunks of BK=64 (2 k-steps), single-buffered B staging
    f32x4 acc[2][5];
#pragma unroll
    for (int m = 0; m < 2; ++m)
#pragma unroll
        for (int j = 0; j < 5; ++j) acc[m][j] = (f32x4)0.f;

    short* b_lds = (short*)bY;
    for (int ch = 0; ch < 8; ++ch) {
        const float4* src = (const float4*)(wpack + (size_t)ch * 2 * NNT * 64 * 8);
        float4* dst = (float4*)bY;
#pragma unroll
        for (int i = 0; i < 10; ++i) dst[tid + 256 * i] = src[tid + 256 * i];
        __syncthreads();
#pragma unroll
        for (int ksl = 0; ksl < 2; ++ksl) {
            int ks = ch * 2 + ksl;
            short8 a0 = *(short8*)&a_lds[((0   + ks) * 64 + lane) * 8];
            short8 a1 = *(short8*)&a_lds[((NKS + ks) * 64 + lane) * 8];
#pragma unroll
            for (int j = 0; j < 5; ++j) {
                short8 b = *(short8*)&b_lds[((ksl * NNT + wv * 5 + j) * 64 + lane) * 8];
                acc[0][j] = __builtin_amdgcn_mfma_f32_16x16x32_bf16(a0, b, acc[0][j], 0, 0, 0);
                acc[1][j] = __builtin_amdgcn_mfma_f32_16x16x32_bf16(a1, b, acc[1][j], 0, 0, 0);
            }
        }
        __syncthreads();
    }

    // ---- write Y tile to LDS (aliases B buffer; safe after last barrier)
    // C/D layout: col = lane&15, row = (lane>>4)*4 + r   [measured m89]
    float* y = (float*)bY;
#pragma unroll
    for (int m = 0; m < 2; ++m) {
        int rowb = m * 16 + (lane >> 4) * 4;
#pragma unroll
        for (int j = 0; j < 5; ++j) {
            int colb = (wv * 5 + j) * 16 + (lane & 15);
#pragma unroll
            for (int r = 0; r < 4; ++r)
                y[(rowb + r) * NC + colb] = acc[m][j][r];
        }
    }
    __syncthreads();

    // ---- per-(row,k) objective: z^T G z - 2 w.z + lamb*reg
#pragma unroll
    for (int it = 0; it < 2; ++it) {
        int item = tid + it * NTHREADS;          // [0,512)
        int kk  = item & (KCLUST - 1);
        int row = item >> 4;
        const float* yy = y + row * NC + kk * 20;
        float z[DLAT], w[DLAT];
#pragma unroll
        for (int i = 0; i < DLAT; ++i) { z[i] = yy[i]; w[i] = yy[DLAT + i]; }
        const float* Gk = G + kk * 100;
        float s = 0.f, wz = 0.f;
#pragma unroll
        for (int i = 0; i < DLAT; ++i) {
            float gz = 0.f;
#pragma unroll
            for (int j = 0; j < DLAT; ++j) gz = fmaf(Gk[i * DLAT + j], z[j], gz);
            s  = fmaf(z[i], gz, s);
            wz = fmaf(w[i], z[i], wz);
        }
        objl[row][kk] = s - 2.f * wz + lreg[kk];
    }
    __syncthreads();

    float v = 0.f;
    if (tid < 32) {
        float m = objl[tid][0];
#pragma unroll
        for (int k = 1; k < KCLUST; ++k) m = fminf(m, objl[tid][k]);
        v = m + rowsq_s[tid];
    }
    red[tid] = v;
    __syncthreads();
    for (int st = NTHREADS / 2; st > 0; st >>= 1) {
        if (tid < st) red[tid] += red[tid + st];
        __syncthreads();
    }
    if (tid == 0) parts[blockIdx.x] = red[0];
}

// ---------------- final deterministic reduction over 512 block partials
__global__ __launch_bounds__(256) void finalize(const float* __restrict__ parts,
                                                float* __restrict__ out) {
    __shared__ float red[256];
    int tid = threadIdx.x;
    red[tid] = parts[tid] + parts[tid + 256];
    __syncthreads();
    for (int st = 128; st > 0; st >>= 1) {
        if (tid < st) red[tid] += red[tid + st];
        __syncthreads();
    }
    if (tid == 0) out[0] = red[0] * (1.0f / BATCH);
}

extern "C" void kernel_launch(void* const* d_in, const int* in_sizes, int n_in,
                              void* d_out, int out_size, void* d_ws, size_t ws_size,
                              hipStream_t stream) {
    const float* x  = (const float*)d_in[0];   // 16384 x 512
    const float* Us = (const float*)d_in[1];   // 16 x 512 x 10
    const float* Vs = (const float*)d_in[2];   // 16 x 10 x 512
    float* out = (float*)d_out;

    // workspace layout: wpack[16*20*64*8] shorts (320KB) | G[1600] | lreg[16] | parts[512]
    short* wpack = (short*)d_ws;
    float* G     = (float*)(wpack + NKS * NNT * 64 * 8);
    float* lreg  = G + KCLUST * 100;
    float* parts = lreg + KCLUST;

    pack_w<<<(NKS * NNT * 64 + 255) / 256, 256, 0, stream>>>(Us, Vs, wpack);
    prep_g<<<KCLUST, 128, 0, stream>>>(Us, Vs, G, lreg);
    main_k<<<BATCH / BM, NTHREADS, 0, stream>>>(x, wpack, G, lreg, parts);
    finalize<<<1, 256, 0, stream>>>(parts, out);
}

// Round 3
// 52.881 us; speedup vs baseline: 3.6838x; 1.2995x over previous
//
#include <hip/hip_runtime.h>

// K-manifold AE cluster objective, fused, bf16-MFMA GEMM, barrier-free K-loop.
// out = mean_b min_k [ ||x_b||^2 - 2 w.z + z^T G z + lamb*reg_k ]
// GEMM: Y[16384][320] = X[16384][512] @ W[512][320], W col 20k+c = Vs/Us concat.
// W pre-packed in B-fragment order -> B frags load straight from L2, no LDS, no barriers.

#define KCLUST   16
#define DAMB     512
#define DLAT     10
#define BATCH    16384
#define NC       320
#define LAMBDA   0.01f

#define BM       64            // batch rows per block
#define NTHREADS 512           // 8 waves: 2 in M x 4 in N
#define NKS      16            // 512/32 k-steps
#define NNT      20            // 320/16 n-tiles
#define YS       324           // padded Y row stride (floats) to break bank conflicts

typedef __attribute__((ext_vector_type(8))) short short8;
typedef __attribute__((ext_vector_type(4))) float f32x4;

__device__ inline short f2bf(float f) {
    unsigned u = __builtin_bit_cast(unsigned, f);
    unsigned r = (u + 0x7FFFu + ((u >> 16) & 1u)) >> 16;
    return (short)r;
}

// ---------------- setup: blocks 0..79 pack W frags; blocks 80..95 compute G/lreg
// wpack[ks][nt][lane][8]: lane l holds B[k = ks*32 + (l>>4)*8 + j][col = nt*16 + (l&15)]
__global__ __launch_bounds__(256) void setup_k(const float* __restrict__ Us,
                                               const float* __restrict__ Vs,
                                               short* __restrict__ wpack,
                                               float* __restrict__ G,
                                               float* __restrict__ lreg) {
    int b = blockIdx.x;
    int tid = threadIdx.x;
    if (b < 80) {
        int idx  = b * 256 + tid;                  // [0, 16*20*64)
        int ks   = idx / (NNT * 64);
        int rem  = idx % (NNT * 64);
        int nt   = rem / 64;
        int lane = rem % 64;
        int col  = nt * 16 + (lane & 15);
        int cl   = col / 20;
        int c    = col % 20;
        short8 sv;
#pragma unroll
        for (int j = 0; j < 8; ++j) {
            int k = ks * 32 + (lane >> 4) * 8 + j;
            float v;
            if (c < DLAT) v = Vs[(size_t)cl * DLAT * DAMB + c * DAMB + k];
            else          v = Us[(size_t)cl * DAMB * DLAT + k * DLAT + (c - DLAT)];
            sv[j] = f2bf(v);
        }
        *(short8*)&wpack[(size_t)idx * 8] = sv;
    } else {
        __shared__ float red[256];
        int k = b - 80;
        const float* Uk = Us + (size_t)k * DAMB * DLAT;
        const float* Vk = Vs + (size_t)k * DLAT * DAMB;
        float s = 0.f;
        for (int i = tid; i < DAMB * DLAT; i += 256) {
            float a = Uk[i], bb = Vk[i];
            s += a * a + bb * bb;
        }
        red[tid] = s;
        __syncthreads();
        for (int st = 128; st > 0; st >>= 1) {
            if (tid < st) red[tid] += red[tid + st];
            __syncthreads();
        }
        if (tid == 0) lreg[k] = LAMBDA * 0.5f * red[0];
        if (tid < DLAT * DLAT) {
            int i = tid / DLAT, j = tid % DLAT;
            float g = 0.f;
            for (int Dv = 0; Dv < DAMB; ++Dv)
                g += Uk[Dv * DLAT + i] * Uk[Dv * DLAT + j];
            G[k * 100 + tid] = g;
        }
    }
}

// ---------------- main: A staged to LDS once; B direct from L2; no K-loop barriers
__global__ __launch_bounds__(NTHREADS, 2) void main_k(const float* __restrict__ x,
                                                      const short* __restrict__ wpack,
                                                      const float* __restrict__ G,
                                                      const float* __restrict__ lreg,
                                                      float* __restrict__ parts) {
    __shared__ short a_lds[4 * NKS * 64 * 8];   // 64 KB: A frags [mt][ks][lane][8]
    __shared__ float y[BM * YS];                // ~81 KB: Y tile, padded stride
    __shared__ float rsqp[BM][8];
    __shared__ float rowsq_s[BM];
    __shared__ float objl[BM][KCLUST];
    __shared__ float red[NTHREADS];

    const int tid  = threadIdx.x;
    const int lane = tid & 63;
    const int wv   = tid >> 6;                  // 0..7
    const int mw   = wv >> 2;                   // 0..1: m-tiles mw*2, mw*2+1
    const int nw   = wv & 3;                    // 0..3: n-tiles nw*5 .. +4
    const int row0 = blockIdx.x * BM;

    // ---- stage A (fp32 -> bf16, fragment order) + exact fp32 rowsq
    {
        const int srow = tid >> 3;              // 0..63
        const int sc   = tid & 7;
        const int mt   = srow >> 4;
        const int rlo  = srow & 15;
        const float* xr = x + (size_t)(row0 + srow) * DAMB;
        float rs = 0.f;
#pragma unroll
        for (int i = 0; i < 8; ++i) {
            int k8 = sc + 8 * i;                // 0..63
            float4 v0 = *(const float4*)(xr + k8 * 8);
            float4 v1 = *(const float4*)(xr + k8 * 8 + 4);
            rs += v0.x * v0.x + v0.y * v0.y + v0.z * v0.z + v0.w * v0.w
                + v1.x * v1.x + v1.y * v1.y + v1.z * v1.z + v1.w * v1.w;
            short8 sv;
            sv[0] = f2bf(v0.x); sv[1] = f2bf(v0.y); sv[2] = f2bf(v0.z); sv[3] = f2bf(v0.w);
            sv[4] = f2bf(v1.x); sv[5] = f2bf(v1.y); sv[6] = f2bf(v1.z); sv[7] = f2bf(v1.w);
            int ks = k8 >> 2, lh = k8 & 3;
            int ln = (lh << 4) | rlo;
            *(short8*)&a_lds[((mt * NKS + ks) * 64 + ln) * 8] = sv;
        }
        rsqp[srow][sc] = rs;
    }
    __syncthreads();
    if (tid < BM) {
        float s = 0.f;
#pragma unroll
        for (int j = 0; j < 8; ++j) s += rsqp[tid][j];
        rowsq_s[tid] = s;
    }

    // ---- K loop: barrier-free; B frags straight from L2
    f32x4 acc[2][5];
#pragma unroll
    for (int m = 0; m < 2; ++m)
#pragma unroll
        for (int j = 0; j < 5; ++j) acc[m][j] = (f32x4)0.f;

#pragma unroll 4
    for (int ks = 0; ks < NKS; ++ks) {
        short8 a0 = *(short8*)&a_lds[(((mw * 2 + 0) * NKS + ks) * 64 + lane) * 8];
        short8 a1 = *(short8*)&a_lds[(((mw * 2 + 1) * NKS + ks) * 64 + lane) * 8];
#pragma unroll
        for (int j = 0; j < 5; ++j) {
            short8 b = *(const short8*)&wpack[(size_t)((ks * NNT + nw * 5 + j) * 64 + lane) * 8];
            acc[0][j] = __builtin_amdgcn_mfma_f32_16x16x32_bf16(a0, b, acc[0][j], 0, 0, 0);
            acc[1][j] = __builtin_amdgcn_mfma_f32_16x16x32_bf16(a1, b, acc[1][j], 0, 0, 0);
        }
    }
    __syncthreads();                     // a_lds dead; Y phase begins

    // ---- write Y tile. C/D layout: col = lane&15, row = (lane>>4)*4 + r
#pragma unroll
    for (int m = 0; m < 2; ++m) {
        int rowb = (mw * 2 + m) * 16 + (lane >> 4) * 4;
#pragma unroll
        for (int j = 0; j < 5; ++j) {
            int colb = (nw * 5 + j) * 16 + (lane & 15);
#pragma unroll
            for (int r = 0; r < 4; ++r)
                y[(rowb + r) * YS + colb] = acc[m][j][r];
        }
    }
    __syncthreads();

    // ---- per-(row,k) objective: z^T G z - 2 w.z + lamb*reg
#pragma unroll
    for (int it = 0; it < 2; ++it) {
        int item = tid + it * NTHREADS;          // [0,1024)
        int kk  = item & (KCLUST - 1);
        int row = item >> 4;
        const float* yy = y + row * YS + kk * 20;
        float z[DLAT], w[DLAT];
#pragma unroll
        for (int i = 0; i < DLAT; ++i) { z[i] = yy[i]; w[i] = yy[DLAT + i]; }
        const float* Gk = G + kk * 100;
        float s = 0.f, wz = 0.f;
#pragma unroll
        for (int i = 0; i < DLAT; ++i) {
            float gz = 0.f;
#pragma unroll
            for (int j = 0; j < DLAT; ++j) gz = fmaf(Gk[i * DLAT + j], z[j], gz);
            s  = fmaf(z[i], gz, s);
            wz = fmaf(w[i], z[i], wz);
        }
        objl[row][kk] = s - 2.f * wz + lreg[kk];
    }
    __syncthreads();

    float v = 0.f;
    if (tid < BM) {
        float m = objl[tid][0];
#pragma unroll
        for (int k = 1; k < KCLUST; ++k) m = fminf(m, objl[tid][k]);
        v = m + rowsq_s[tid];
    }
    red[tid] = v;
    __syncthreads();
    for (int st = NTHREADS / 2; st > 0; st >>= 1) {
        if (tid < st) red[tid] += red[tid + st];
        __syncthreads();
    }
    if (tid == 0) parts[blockIdx.x] = red[0];
}

// ---------------- final deterministic reduction over 256 block partials
__global__ __launch_bounds__(256) void finalize(const float* __restrict__ parts,
                                                float* __restrict__ out) {
    __shared__ float red[256];
    int tid = threadIdx.x;
    red[tid] = parts[tid];
    __syncthreads();
    for (int st = 128; st > 0; st >>= 1) {
        if (tid < st) red[tid] += red[tid + st];
        __syncthreads();
    }
    if (tid == 0) out[0] = red[0] * (1.0f / BATCH);
}

extern "C" void kernel_launch(void* const* d_in, const int* in_sizes, int n_in,
                              void* d_out, int out_size, void* d_ws, size_t ws_size,
                              hipStream_t stream) {
    const float* x  = (const float*)d_in[0];   // 16384 x 512
    const float* Us = (const float*)d_in[1];   // 16 x 512 x 10
    const float* Vs = (const float*)d_in[2];   // 16 x 10 x 512
    float* out = (float*)d_out;

    // workspace: wpack[20480*8] shorts (320KB) | G[1600] | lreg[16] | parts[256]
    short* wpack = (short*)d_ws;
    float* G     = (float*)(wpack + NKS * NNT * 64 * 8);
    float* lreg  = G + KCLUST * 100;
    float* parts = lreg + KCLUST;

    setup_k<<<96, 256, 0, stream>>>(Us, Vs, wpack, G, lreg);
    main_k<<<BATCH / BM, NTHREADS, 0, stream>>>(x, wpack, G, lreg, parts);
    finalize<<<1, 256, 0, stream>>>(parts, out);
}